// Round 12
// baseline (120.193 us; speedup 1.0000x reference)
//
#include <hip/hip_runtime.h>
#include <stdint.h>

#define IN_DIM 2048
#define OUT_DIM 2048
#define BATCH 4096
#define KDIM (2 * IN_DIM)   // 4096
#define KROWB (KDIM * 2)    // 8192 bytes per bf16 row
#define BN_EPS 1e-5f

typedef __attribute__((ext_vector_type(8))) short bf16x8;
typedef __attribute__((ext_vector_type(4))) float f32x4;

__device__ __forceinline__ unsigned short f2bf(float f) {
  union { float f; unsigned u; } v; v.f = f;
  unsigned r = v.u + 0x7FFFu + ((v.u >> 16) & 1u);  // RNE
  return (unsigned short)(r >> 16);
}

// K1a: A = [wavelet(x) | x] bf16, row-major (BATCH x KDIM)
__global__ void prep_act(const float* __restrict__ x,
                         const float* __restrict__ scale,
                         const float* __restrict__ translate,
                         unsigned short* __restrict__ A) {
  int e = (blockIdx.x * 256 + threadIdx.x) * 4;
  int b = e / IN_DIM;
  int i = e % IN_DIM;
  float4 xv = *(const float4*)(x + e);
  float4 sv = *(const float4*)(scale + i);
  float4 tv = *(const float4*)(translate + i);
  const float c = 0.7511255444649425f;  // pi^-0.25
  float u0 = (xv.x - tv.x) / fmaxf(sv.x, 1e-3f);
  float u1 = (xv.y - tv.y) / fmaxf(sv.y, 1e-3f);
  float u2 = (xv.z - tv.z) / fmaxf(sv.z, 1e-3f);
  float u3 = (xv.w - tv.w) / fmaxf(sv.w, 1e-3f);
  ushort4 wv, xb;
  wv.x = f2bf(c * __cosf(3.0f * u0) * __expf(-0.5f * u0 * u0));
  wv.y = f2bf(c * __cosf(3.0f * u1) * __expf(-0.5f * u1 * u1));
  wv.z = f2bf(c * __cosf(3.0f * u2) * __expf(-0.5f * u2 * u2));
  wv.w = f2bf(c * __cosf(3.0f * u3) * __expf(-0.5f * u3 * u3));
  xb.x = f2bf(xv.x); xb.y = f2bf(xv.y); xb.z = f2bf(xv.z); xb.w = f2bf(xv.w);
  *(ushort4*)(A + (size_t)b * KDIM + i) = wv;
  *(ushort4*)(A + (size_t)b * KDIM + IN_DIM + i) = xb;
}

// K1b: W = [wave_weight | 0.3*base_weight] bf16, row-major (OUT_DIM x KDIM)
__global__ void prep_w(const float* __restrict__ ww,
                       const float* __restrict__ bw,
                       unsigned short* __restrict__ W) {
  int e = (blockIdx.x * 256 + threadIdx.x) * 4;
  int o = e / IN_DIM;
  int k = e % IN_DIM;
  float4 a = *(const float4*)(ww + e);
  float4 b = *(const float4*)(bw + e);
  ushort4 wa, wb;
  wa.x = f2bf(a.x); wa.y = f2bf(a.y); wa.z = f2bf(a.z); wa.w = f2bf(a.w);
  wb.x = f2bf(0.3f * b.x); wb.y = f2bf(0.3f * b.y);
  wb.z = f2bf(0.3f * b.z); wb.w = f2bf(0.3f * b.w);
  *(ushort4*)(W + (size_t)o * KDIM + k) = wa;
  *(ushort4*)(W + (size_t)o * KDIM + IN_DIM + k) = wb;
}

// ---- full-K 128x128 GEMM, 2 waves of 64x128, BK=32, 3 blocks/CU TLP ----
// 512 blocks (grid 32x16), 128 threads. LDS = 3-slot ring x 16KB = 48KB ->
// 3 blocks/CU co-resident; independent blocks' barriers don't couple, so
// one block's MFMA overlaps another's LDS reads / staging.
// Slot 16KB: A @0 (128 rows x 32k), B @8192 (128 rows). Paired-row storage
// (R6/R11-proven, 0 conflicts):
//   byte = (row>>1)*128 + (row&1)*64 + ((kslot ^ ((row>>1)&3))<<4)
// Tile t reads slot t%3, stages t+2 into slot (t+2)%3 (its last reads were
// at t-1, behind t-1's lgkmcnt(0)+barrier). 8 GLDS/thread/tile; at tile end
// outstanding = 16 -> vmcnt(8) drains exactly tile t+1's stage. 1 barrier.
// Full-K acc in registers -> fused batch stats are exact.

#define GLDS(gp, lo) __builtin_amdgcn_global_load_lds( \
    (const __attribute__((address_space(1))) void*)(gp), \
    (__attribute__((address_space(3))) void*)(lds + (lo) + ldsw), 16, 0, 0)

#define MM32() do { \
  __builtin_amdgcn_s_setprio(1); \
  _Pragma("unroll") for (int i2 = 0; i2 < 4; ++i2) \
  _Pragma("unroll") for (int j2 = 0; j2 < 8; ++j2) \
    acc[i2][j2] = __builtin_amdgcn_mfma_f32_16x16x32_bf16( \
        af[i2], bq[j2], acc[i2][j2], 0, 0, 0); \
  __builtin_amdgcn_s_setprio(0); \
} while (0)

#define LGKM0() asm volatile("s_waitcnt lgkmcnt(0)" ::: "memory")
#define VMW8()  asm volatile("s_waitcnt vmcnt(8)" ::: "memory")
#define VMW0()  asm volatile("s_waitcnt vmcnt(0)" ::: "memory")
#define NOW()   do { } while (0)
#define BAR()   do { asm volatile("" ::: "memory"); __builtin_amdgcn_s_barrier(); \
                     asm volatile("" ::: "memory"); } while (0)

// S = read slot, SS = stage slot, TOFS = byte offset of staged tile (t+2)
#define KT(S, SS, TOFS, DOST, TAILW) do { \
  const char* Lr = lds + (S) * 16384; \
  af[0] = *(const bf16x8*)(Lr + aoff + 0 * 1024 + roff); \
  af[1] = *(const bf16x8*)(Lr + aoff + 1 * 1024 + roff); \
  af[2] = *(const bf16x8*)(Lr + aoff + 2 * 1024 + roff); \
  af[3] = *(const bf16x8*)(Lr + aoff + 3 * 1024 + roff); \
  bq[0] = *(const bf16x8*)(Lr + 8192 + 0 * 1024 + roff); \
  bq[1] = *(const bf16x8*)(Lr + 8192 + 1 * 1024 + roff); \
  bq[2] = *(const bf16x8*)(Lr + 8192 + 2 * 1024 + roff); \
  bq[3] = *(const bf16x8*)(Lr + 8192 + 3 * 1024 + roff); \
  bq[4] = *(const bf16x8*)(Lr + 8192 + 4 * 1024 + roff); \
  bq[5] = *(const bf16x8*)(Lr + 8192 + 5 * 1024 + roff); \
  bq[6] = *(const bf16x8*)(Lr + 8192 + 6 * 1024 + roff); \
  bq[7] = *(const bf16x8*)(Lr + 8192 + 7 * 1024 + roff); \
  if (DOST) { \
    GLDS(aG + (TOFS),              (SS) * 16384 + 0); \
    GLDS(aG + (TOFS) + 32 * KROWB, (SS) * 16384 + 2048); \
    GLDS(aG + (TOFS) + 64 * KROWB, (SS) * 16384 + 4096); \
    GLDS(aG + (TOFS) + 96 * KROWB, (SS) * 16384 + 6144); \
    GLDS(bG + (TOFS),              (SS) * 16384 + 8192); \
    GLDS(bG + (TOFS) + 32 * KROWB, (SS) * 16384 + 10240); \
    GLDS(bG + (TOFS) + 64 * KROWB, (SS) * 16384 + 12288); \
    GLDS(bG + (TOFS) + 96 * KROWB, (SS) * 16384 + 14336); \
  } \
  MM32(); \
  LGKM0(); TAILW; BAR(); \
} while (0)

__global__ __launch_bounds__(128, 1) void gemm128(
    const unsigned short* __restrict__ A,
    const unsigned short* __restrict__ W,
    float* __restrict__ Y,
    float* __restrict__ sums, float* __restrict__ sqs) {
  __shared__ char lds[49152];
  const int tid = threadIdx.x;
  const int lane = tid & 63;
  const int w = tid >> 6;   // wave 0/1 -> 64-row M half

  // XCD swizzle: xcd gets a 2-bcol slab (256 cols, B slab 2MB L2-resident)
  // x all 32 brow positions.
  const int xcd = blockIdx.x & 7;
  const int li = blockIdx.x >> 3;            // 0..63
  const int bcol = (xcd * 2 + (li >> 5)) * 128;
  const int brow = (li & 31) * 128;

  // staging: thread tid covers bytes tid*16 (+i*2048) of each 8KB region:
  // line lr = (tid>>3) + 16i, half = (tid>>2)&1, pos = tid&3
  // -> global row = 2*(tid>>3) + 32i + half, kslot = (tid&3) ^ ((tid>>3)&3)
  const int srow2 = 2 * (tid >> 3) + ((tid >> 2) & 1);
  const int sksl = (tid & 3) ^ ((tid >> 3) & 3);
  const char* aG = (const char*)A + (size_t)(brow + srow2) * KROWB + sksl * 16;
  const char* bG = (const char*)W + (size_t)(bcol + srow2) * KROWB + sksl * 16;
  const int ldsw = w * 1024;  // + lane*16 implicit in global_load_lds

  // fragment read: row = base + f*16 + (lane&15), kslot = lane>>4
  // byte = (row>>1)*128 + (row&1)*64 + ((kslot ^ ((row>>1)&3))<<4)
  const int lh = (lane & 15) >> 1;
  const int roff = lh * 128 + (lane & 1) * 64 + (((lane >> 4) ^ (lh & 3)) << 4);
  const int aoff = w * 4096;  // wave's 64-row A half

  f32x4 acc[4][8];
#pragma unroll
  for (int m = 0; m < 4; ++m)
#pragma unroll
    for (int n = 0; n < 8; ++n)
      acc[m][n] = (f32x4){0.f, 0.f, 0.f, 0.f};
  bf16x8 af[4], bq[8];

  // prologue: stage tiles 0 (slot 0) and 1 (slot 1); vmcnt(8) -> tile 0 in.
  GLDS(aG, 0); GLDS(aG + 32 * KROWB, 2048);
  GLDS(aG + 64 * KROWB, 4096); GLDS(aG + 96 * KROWB, 6144);
  GLDS(bG, 8192); GLDS(bG + 32 * KROWB, 10240);
  GLDS(bG + 64 * KROWB, 12288); GLDS(bG + 96 * KROWB, 14336);
  GLDS(aG + 64, 16384); GLDS(aG + 32 * KROWB + 64, 16384 + 2048);
  GLDS(aG + 64 * KROWB + 64, 16384 + 4096); GLDS(aG + 96 * KROWB + 64, 16384 + 6144);
  GLDS(bG + 64, 16384 + 8192); GLDS(bG + 32 * KROWB + 64, 16384 + 10240);
  GLDS(bG + 64 * KROWB + 64, 16384 + 12288); GLDS(bG + 96 * KROWB + 64, 16384 + 14336);
  VMW8(); BAR();

  for (int tt = 0; tt < 123; tt += 3) {   // tiles 0..122, stage t+2
    KT(0, 2, (tt + 2) * 64, 1, VMW8());
    KT(1, 0, (tt + 3) * 64, 1, VMW8());
    KT(2, 1, (tt + 4) * 64, 1, VMW8());
  }
  KT(0, 2, 125 * 64, 1, VMW8());  // t=123 stages 125
  KT(1, 0, 126 * 64, 1, VMW8());  // t=124 stages 126
  KT(2, 1, 127 * 64, 1, VMW8());  // t=125 stages 127
  KT(0, 0, 0, 0, VMW0());         // t=126
  KT(1, 0, 0, 0, NOW());          // t=127

  // epilogue: C/D col = lane&15, row = (lane>>4)*4 + j; Y write + exact stats
  const int r0 = brow + w * 64 + (lane >> 4) * 4;
  const int c0 = bcol + (lane & 15);
#pragma unroll
  for (int m = 0; m < 4; ++m)
#pragma unroll
    for (int n = 0; n < 8; ++n)
#pragma unroll
      for (int j = 0; j < 4; ++j)
        Y[(size_t)(r0 + m * 16 + j) * OUT_DIM + (c0 + n * 16)] = acc[m][n][j];

  // fused column stats: lanes l, l^16, l^32, l^48 share a column.
#pragma unroll
  for (int n = 0; n < 8; ++n) {
    float s = 0.f, q = 0.f;
#pragma unroll
    for (int m = 0; m < 4; ++m)
#pragma unroll
      for (int j = 0; j < 4; ++j) {
        float v = acc[m][n][j];
        s += v; q += v * v;
      }
    s += __shfl_xor(s, 16); q += __shfl_xor(q, 16);
    s += __shfl_xor(s, 32); q += __shfl_xor(q, 32);
    if (lane < 16) {
      atomicAdd(&sums[c0 + n * 16], s);
      atomicAdd(&sqs[c0 + n * 16], q);
    }
  }
}

// K3: batchnorm on Y in-place
__global__ void bnorm(float* __restrict__ Y,
                      const float* __restrict__ sums, const float* __restrict__ sqs,
                      const float* __restrict__ gamma, const float* __restrict__ beta) {
  int e = (blockIdx.x * 256 + threadIdx.x) * 4;
  int c = e % OUT_DIM;
  float4 y = *(float4*)(Y + e);
  float4 s = *(const float4*)(sums + c);
  float4 q = *(const float4*)(sqs + c);
  float4 g = *(const float4*)(gamma + c);
  float4 bb = *(const float4*)(beta + c);
  const float invB = 1.0f / (float)BATCH;
  float m0 = s.x * invB, m1 = s.y * invB, m2 = s.z * invB, m3 = s.w * invB;
  float i0 = rsqrtf(q.x * invB - m0 * m0 + BN_EPS);
  float i1 = rsqrtf(q.y * invB - m1 * m1 + BN_EPS);
  float i2 = rsqrtf(q.z * invB - m2 * m2 + BN_EPS);
  float i3 = rsqrtf(q.w * invB - m3 * m3 + BN_EPS);
  y.x = g.x * (y.x - m0) * i0 + bb.x;
  y.y = g.y * (y.y - m1) * i1 + bb.y;
  y.z = g.z * (y.z - m2) * i2 + bb.z;
  y.w = g.w * (y.w - m3) * i3 + bb.w;
  *(float4*)(Y + e) = y;
}

extern "C" void kernel_launch(void* const* d_in, const int* in_sizes, int n_in,
                              void* d_out, int out_size, void* d_ws, size_t ws_size,
                              hipStream_t stream) {
  const float* x         = (const float*)d_in[0];
  const float* scale     = (const float*)d_in[1];
  const float* translate = (const float*)d_in[2];
  const float* ww        = (const float*)d_in[3];
  const float* bw        = (const float*)d_in[4];
  const float* gamma     = (const float*)d_in[5];
  const float* beta      = (const float*)d_in[6];
  float* out = (float*)d_out;

  char* ws = (char*)d_ws;
  unsigned short* A = (unsigned short*)ws;                 // 33,554,432 B
  unsigned short* W = (unsigned short*)(ws + 33554432);    // 16,777,216 B
  float* sums = (float*)(ws + 50331648);
  float* sqs  = sums + OUT_DIM;

  hipMemsetAsync(sums, 0, 2 * OUT_DIM * sizeof(float), stream);
  prep_act<<<(BATCH * IN_DIM) / 1024, 256, 0, stream>>>(x, scale, translate, A);
  prep_w<<<(OUT_DIM * IN_DIM) / 1024, 256, 0, stream>>>(ww, bw, W);
  gemm128<<<512, 128, 0, stream>>>(A, W, out, sums, sqs);
  bnorm<<<(BATCH * OUT_DIM) / 1024, 256, 0, stream>>>(out, sums, sqs, gamma, beta);
}

// Round 13
// 109.568 us; speedup vs baseline: 1.0970x; 1.0970x over previous
//
#include <hip/hip_runtime.h>
#include <stdint.h>

#define IN_DIM 2048
#define OUT_DIM 2048
#define BATCH 4096
#define KDIM (2 * IN_DIM)   // 4096
#define KROWB (KDIM * 2)    // 8192 bytes per bf16 row
#define BN_EPS 1e-5f

typedef __attribute__((ext_vector_type(8))) short bf16x8;
typedef __attribute__((ext_vector_type(4))) float f32x4;

__device__ __forceinline__ unsigned short f2bf(float f) {
  union { float f; unsigned u; } v; v.f = f;
  unsigned r = v.u + 0x7FFFu + ((v.u >> 16) & 1u);  // RNE
  return (unsigned short)(r >> 16);
}

// K1: merged prep. Blocks [0, 8192) build A = [wavelet(x) | x];
// blocks [8192, 12288) build W = [wave_weight | 0.3*base_weight].
__global__ void prep_all(const float* __restrict__ x,
                         const float* __restrict__ scale,
                         const float* __restrict__ translate,
                         const float* __restrict__ ww,
                         const float* __restrict__ bw,
                         unsigned short* __restrict__ A,
                         unsigned short* __restrict__ W) {
  if (blockIdx.x < 8192) {
    int e = (blockIdx.x * 256 + threadIdx.x) * 4;
    int b = e / IN_DIM;
    int i = e % IN_DIM;
    float4 xv = *(const float4*)(x + e);
    float4 sv = *(const float4*)(scale + i);
    float4 tv = *(const float4*)(translate + i);
    const float c = 0.7511255444649425f;  // pi^-0.25
    float u0 = (xv.x - tv.x) / fmaxf(sv.x, 1e-3f);
    float u1 = (xv.y - tv.y) / fmaxf(sv.y, 1e-3f);
    float u2 = (xv.z - tv.z) / fmaxf(sv.z, 1e-3f);
    float u3 = (xv.w - tv.w) / fmaxf(sv.w, 1e-3f);
    ushort4 wv, xb;
    wv.x = f2bf(c * __cosf(3.0f * u0) * __expf(-0.5f * u0 * u0));
    wv.y = f2bf(c * __cosf(3.0f * u1) * __expf(-0.5f * u1 * u1));
    wv.z = f2bf(c * __cosf(3.0f * u2) * __expf(-0.5f * u2 * u2));
    wv.w = f2bf(c * __cosf(3.0f * u3) * __expf(-0.5f * u3 * u3));
    xb.x = f2bf(xv.x); xb.y = f2bf(xv.y); xb.z = f2bf(xv.z); xb.w = f2bf(xv.w);
    *(ushort4*)(A + (size_t)b * KDIM + i) = wv;
    *(ushort4*)(A + (size_t)b * KDIM + IN_DIM + i) = xb;
  } else {
    int e = ((blockIdx.x - 8192) * 256 + threadIdx.x) * 4;
    int o = e / IN_DIM;
    int k = e % IN_DIM;
    float4 a = *(const float4*)(ww + e);
    float4 b = *(const float4*)(bw + e);
    ushort4 wa, wb;
    wa.x = f2bf(a.x); wa.y = f2bf(a.y); wa.z = f2bf(a.z); wa.w = f2bf(a.w);
    wb.x = f2bf(0.3f * b.x); wb.y = f2bf(0.3f * b.y);
    wb.z = f2bf(0.3f * b.z); wb.w = f2bf(0.3f * b.w);
    *(ushort4*)(W + (size_t)o * KDIM + k) = wa;
    *(ushort4*)(W + (size_t)o * KDIM + IN_DIM + k) = wb;
  }
}

// ---- full-K 256x128 GEMM, in-block K-split: 8 waves = 2 K-groups x 4 ----
// Group g (4 waves, 2Mx2N of 128x64, 16x16x32 MFMA) accumulates
// K in [g*2048, (g+1)*2048) with its own 3-slot LDS ring at g*73728.
// Slot 24KB: A @0 (256 rows), B @16384 (128 rows). BK=32 -> 64B/row,
// paired-row storage (0 conflicts):
//   byte = (row>>1)*128 + (row&1)*64 + ((kslot ^ ((row>>1)&3))<<4)
// Tile t reads slot t%3, stages t+2 into slot (t+2)%3 (disjoint; its last
// reads ended behind tile t-1's lgkmcnt(0)+barrier). Stage issues at the
// TOP of each tile (R13: maximizes prefetch age). 6 GLDS/thread/tile;
// merged s_waitcnt vmcnt(6) lgkmcnt(0) at tile end drains exactly tile
// t+1's stage (issued 2 tiles earlier). ONE barrier/tile.
// Epilogue: group1 dumps acc to LDS; group0 adds -> full-K sums in
// registers -> exact fused batch stats; group0 stores Y + atomics.

#define GLDS(gp, lo) __builtin_amdgcn_global_load_lds( \
    (const __attribute__((address_space(1))) void*)(gp), \
    (__attribute__((address_space(3))) void*)(lds + (lo) + ldsw), 16, 0, 0)

#define MM16(mh) do { \
  __builtin_amdgcn_s_setprio(1); \
  _Pragma("unroll") for (int i2 = 0; i2 < 4; ++i2) \
  _Pragma("unroll") for (int j2 = 0; j2 < 4; ++j2) \
    acc[(mh) * 4 + i2][j2] = __builtin_amdgcn_mfma_f32_16x16x32_bf16( \
        af[i2], bq[j2], acc[(mh) * 4 + i2][j2], 0, 0, 0); \
  __builtin_amdgcn_s_setprio(0); \
} while (0)

#define WAIT_V6L0() asm volatile("s_waitcnt vmcnt(6) lgkmcnt(0)" ::: "memory")
#define WAIT_V0L0() asm volatile("s_waitcnt vmcnt(0) lgkmcnt(0)" ::: "memory")
#define WAIT_L0()   asm volatile("s_waitcnt lgkmcnt(0)" ::: "memory")
#define BAR()   do { asm volatile("" ::: "memory"); __builtin_amdgcn_s_barrier(); \
                     asm volatile("" ::: "memory"); } while (0)

// S = read slot, SS = stage slot, TOFS = byte offset of staged tile (t+2)
#define KT(S, SS, TOFS, DOST, TAILW) do { \
  if (DOST) { \
    GLDS(aG + (TOFS),               gbase + (SS) * 24576 + 0); \
    GLDS(aG + (TOFS) +  64 * KROWB, gbase + (SS) * 24576 + 4096); \
    GLDS(aG + (TOFS) + 128 * KROWB, gbase + (SS) * 24576 + 8192); \
    GLDS(aG + (TOFS) + 192 * KROWB, gbase + (SS) * 24576 + 12288); \
    GLDS(bG + (TOFS),               gbase + (SS) * 24576 + 16384); \
    GLDS(bG + (TOFS) +  64 * KROWB, gbase + (SS) * 24576 + 20480); \
  } \
  { \
    const char* Lr = lds + gbase + (S) * 24576; \
    af[0] = *(const bf16x8*)(Lr + aoff + 0 * 1024 + roff); \
    af[1] = *(const bf16x8*)(Lr + aoff + 1 * 1024 + roff); \
    af[2] = *(const bf16x8*)(Lr + aoff + 2 * 1024 + roff); \
    af[3] = *(const bf16x8*)(Lr + aoff + 3 * 1024 + roff); \
    bq[0] = *(const bf16x8*)(Lr + boff + 0 * 1024 + roff); \
    bq[1] = *(const bf16x8*)(Lr + boff + 1 * 1024 + roff); \
    bq[2] = *(const bf16x8*)(Lr + boff + 2 * 1024 + roff); \
    bq[3] = *(const bf16x8*)(Lr + boff + 3 * 1024 + roff); \
    MM16(0); \
    af[0] = *(const bf16x8*)(Lr + aoff + 4096 + 0 * 1024 + roff); \
    af[1] = *(const bf16x8*)(Lr + aoff + 4096 + 1 * 1024 + roff); \
    af[2] = *(const bf16x8*)(Lr + aoff + 4096 + 2 * 1024 + roff); \
    af[3] = *(const bf16x8*)(Lr + aoff + 4096 + 3 * 1024 + roff); \
    MM16(1); \
  } \
  TAILW; BAR(); \
} while (0)

__global__ __launch_bounds__(512, 2) void gemm_ksplit(
    const unsigned short* __restrict__ A,
    const unsigned short* __restrict__ W,
    float* __restrict__ Y,
    float* __restrict__ sums, float* __restrict__ sqs) {
  __shared__ char lds[147456];
  const int tid = threadIdx.x;
  const int lane = tid & 63;
  const int g = tid >> 8;          // K-group 0/1
  const int gt = tid & 255;        // thread-in-group
  const int w4 = (tid >> 6) & 3;   // wave-in-group
  const int wm = w4 >> 1;          // 0..1 -> 128-row M half
  const int wn = w4 & 1;           // 0..1 -> 64-col N half
  const int gbase = g * 73728;

  // XCD-aware swizzle: 16x16 block grid tiled in 4x8 chunks, one per XCD.
  const int xcd = blockIdx.x & 7;
  const int li = blockIdx.x >> 3;           // 0..31
  const int brow = ((xcd >> 1) * 4 + (li >> 3)) * 256;
  const int bcol = ((xcd & 1) * 8 + (li & 7)) * 128;

  // staging: thread gt covers unit byte gt*16 per 4KB chunk:
  // lds_line lr = gt>>3, half = (gt>>2)&1, pos = gt&3
  // -> global row = 2*lr + half, kslot = pos ^ (lr&3)
  const int srow2 = 2 * (gt >> 3) + ((gt >> 2) & 1);
  const int sksl = (gt & 3) ^ ((gt >> 3) & 3);
  const char* aG = (const char*)A + (size_t)(brow + srow2) * KROWB + g * 4096 + sksl * 16;
  const char* bG = (const char*)W + (size_t)(bcol + srow2) * KROWB + g * 4096 + sksl * 16;
  const int ldsw = w4 * 1024;  // + lane*16 implicit in global_load_lds

  // fragment read: row = base + f*16 + (lane&15), kslot = lane>>4 (K32)
  // byte = (row>>1)*128 + (row&1)*64 + ((kslot ^ ((row>>1)&3))<<4)
  const int lh = (lane & 15) >> 1;
  const int roff = lh * 128 + (lane & 1) * 64 + (((lane >> 4) ^ (lh & 3)) << 4);
  const int aoff = wm * 8192;             // A unit: 128-row half = 8KB
  const int boff = 16384 + wn * 4096;     // B unit: 64-row half = 4KB

  f32x4 acc[8][4];
#pragma unroll
  for (int m = 0; m < 8; ++m)
#pragma unroll
    for (int n = 0; n < 4; ++n)
      acc[m][n] = (f32x4){0.f, 0.f, 0.f, 0.f};
  bf16x8 af[4], bq[4];

  // prologue: stage tiles 0 (slot 0) and 1 (slot 1) into this group's ring;
  // vmcnt(6) -> tile 0 landed.
  GLDS(aG, gbase + 0); GLDS(aG + 64 * KROWB, gbase + 4096);
  GLDS(aG + 128 * KROWB, gbase + 8192); GLDS(aG + 192 * KROWB, gbase + 12288);
  GLDS(bG, gbase + 16384); GLDS(bG + 64 * KROWB, gbase + 20480);
  GLDS(aG + 64, gbase + 24576);
  GLDS(aG + 64 * KROWB + 64, gbase + 24576 + 4096);
  GLDS(aG + 128 * KROWB + 64, gbase + 24576 + 8192);
  GLDS(aG + 192 * KROWB + 64, gbase + 24576 + 12288);
  GLDS(bG + 64, gbase + 24576 + 16384);
  GLDS(bG + 64 * KROWB + 64, gbase + 24576 + 20480);
  asm volatile("s_waitcnt vmcnt(6)" ::: "memory"); BAR();

  for (int tt = 0; tt < 60; tt += 3) {   // tiles 0..59, stage t+2
    KT(0, 2, (tt + 2) * 64, 1, WAIT_V6L0());
    KT(1, 0, (tt + 3) * 64, 1, WAIT_V6L0());
    KT(2, 1, (tt + 4) * 64, 1, WAIT_V6L0());
  }
  KT(0, 2, 62 * 64, 1, WAIT_V6L0());  // t=60 stages 62
  KT(1, 0, 63 * 64, 1, WAIT_V6L0());  // t=61 stages 63
  KT(2, 0, 0, 0, WAIT_V0L0());        // t=62
  KT(0, 0, 0, 0, WAIT_L0());          // t=63

  // ---- K-combine: group1 dumps acc; group0 adds, stores, does stats ----
  if (g == 1) {
#pragma unroll
    for (int m = 0; m < 8; ++m)
#pragma unroll
      for (int n = 0; n < 4; ++n)
        *(f32x4*)(lds + w4 * 32768 + (m * 4 + n) * 1024 + lane * 16) = acc[m][n];
  }
  WAIT_L0(); BAR();
  if (g == 0) {
#pragma unroll
    for (int m = 0; m < 8; ++m)
#pragma unroll
      for (int n = 0; n < 4; ++n) {
        f32x4 p = *(const f32x4*)(lds + w4 * 32768 + (m * 4 + n) * 1024 + lane * 16);
        acc[m][n] += p;
      }

    const int r0 = brow + wm * 128 + (lane >> 4) * 4;
    const int c0 = bcol + wn * 64 + (lane & 15);
#pragma unroll
    for (int m = 0; m < 8; ++m)
#pragma unroll
      for (int n = 0; n < 4; ++n)
#pragma unroll
        for (int j = 0; j < 4; ++j)
          Y[(size_t)(r0 + m * 16 + j) * OUT_DIM + (c0 + n * 16)] = acc[m][n][j];

    // fused column stats (full-K sums -> exact variance). Lanes l, l^16,
    // l^32, l^48 share a column; reduce, atomics from lane<16.
#pragma unroll
    for (int n = 0; n < 4; ++n) {
      float s = 0.f, q = 0.f;
#pragma unroll
      for (int m = 0; m < 8; ++m)
#pragma unroll
        for (int j = 0; j < 4; ++j) {
          float v = acc[m][n][j];
          s += v; q += v * v;
        }
      s += __shfl_xor(s, 16); q += __shfl_xor(q, 16);
      s += __shfl_xor(s, 32); q += __shfl_xor(q, 32);
      if (lane < 16) {
        atomicAdd(&sums[c0 + n * 16], s);
        atomicAdd(&sqs[c0 + n * 16], q);
      }
    }
  }
}

// K3: batchnorm on Y in-place
__global__ void bnorm(float* __restrict__ Y,
                      const float* __restrict__ sums, const float* __restrict__ sqs,
                      const float* __restrict__ gamma, const float* __restrict__ beta) {
  int e = (blockIdx.x * 256 + threadIdx.x) * 4;
  int c = e % OUT_DIM;
  float4 y = *(float4*)(Y + e);
  float4 s = *(const float4*)(sums + c);
  float4 q = *(const float4*)(sqs + c);
  float4 g = *(const float4*)(gamma + c);
  float4 bb = *(const float4*)(beta + c);
  const float invB = 1.0f / (float)BATCH;
  float m0 = s.x * invB, m1 = s.y * invB, m2 = s.z * invB, m3 = s.w * invB;
  float i0 = rsqrtf(q.x * invB - m0 * m0 + BN_EPS);
  float i1 = rsqrtf(q.y * invB - m1 * m1 + BN_EPS);
  float i2 = rsqrtf(q.z * invB - m2 * m2 + BN_EPS);
  float i3 = rsqrtf(q.w * invB - m3 * m3 + BN_EPS);
  y.x = g.x * (y.x - m0) * i0 + bb.x;
  y.y = g.y * (y.y - m1) * i1 + bb.y;
  y.z = g.z * (y.z - m2) * i2 + bb.z;
  y.w = g.w * (y.w - m3) * i3 + bb.w;
  *(float4*)(Y + e) = y;
}

extern "C" void kernel_launch(void* const* d_in, const int* in_sizes, int n_in,
                              void* d_out, int out_size, void* d_ws, size_t ws_size,
                              hipStream_t stream) {
  const float* x         = (const float*)d_in[0];
  const float* scale     = (const float*)d_in[1];
  const float* translate = (const float*)d_in[2];
  const float* ww        = (const float*)d_in[3];
  const float* bw        = (const float*)d_in[4];
  const float* gamma     = (const float*)d_in[5];
  const float* beta      = (const float*)d_in[6];
  float* out = (float*)d_out;

  char* ws = (char*)d_ws;
  unsigned short* A = (unsigned short*)ws;                 // 33,554,432 B
  unsigned short* W = (unsigned short*)(ws + 33554432);    // 16,777,216 B
  float* sums = (float*)(ws + 50331648);
  float* sqs  = sums + OUT_DIM;

  hipMemsetAsync(sums, 0, 2 * OUT_DIM * sizeof(float), stream);
  prep_all<<<12288, 256, 0, stream>>>(x, scale, translate, ww, bw, A, W);
  gemm_ksplit<<<256, 512, 0, stream>>>(A, W, out, sums, sqs);
  bnorm<<<(BATCH * OUT_DIM) / 1024, 256, 0, stream>>>(out, sums, sqs, gamma, beta);
}